// Round 9
// baseline (543.293 us; speedup 1.0000x reference)
//
#include <hip/hip_runtime.h>

// Problem constants
#define B_   4
#define NQ_  2048
#define NKV_ 2048
#define H_   16
#define DK_  64
#define DM_  1024
#define DKV_ 2048   // stacked K|V projection width

typedef _Float16 f16x8 __attribute__((ext_vector_type(8)));
typedef _Float16 f16x4 __attribute__((ext_vector_type(4)));
typedef float    f32x4 __attribute__((ext_vector_type(4)));

__device__ __forceinline__ void gload_lds16(const void* g, void* l) {
  __builtin_amdgcn_global_load_lds(
      (const __attribute__((address_space(1))) unsigned int*)g,
      (__attribute__((address_space(3))) unsigned int*)l, 16, 0, 0);
}

// ---------------- cast f32 -> f16 (4 elems/thread) ----------------
__global__ __launch_bounds__(256) void cast_f16(const float* __restrict__ in,
                                                _Float16* __restrict__ out, int n4) {
  int i = blockIdx.x * 256 + threadIdx.x;
  if (i >= n4) return;
  float4 v = ((const float4*)in)[i];
  f16x4 o = {(_Float16)v.x, (_Float16)v.y, (_Float16)v.z, (_Float16)v.w};
  *(f16x4*)(out + (size_t)i * 4) = o;
}

// ---------------- W [K][N] f32 -> Wt [N][K] f16 ----------------
__global__ __launch_bounds__(256) void wtrans(const float* __restrict__ W,
                                              _Float16* __restrict__ Wt) {
  __shared__ float tile[32][33];
  int bx = blockIdx.x & 31, by = blockIdx.x >> 5;
  int tx = threadIdx.x & 31, ty = threadIdx.x >> 5;  // ty 0..7
#pragma unroll
  for (int j = 0; j < 4; ++j)
    tile[ty + j * 8][tx] = W[(size_t)(by * 32 + ty + j * 8) * 1024 + bx * 32 + tx];
  __syncthreads();
#pragma unroll
  for (int j = 0; j < 4; ++j)
    Wt[(size_t)(bx * 32 + ty + j * 8) * 1024 + by * 32 + tx] = (_Float16)tile[tx][ty + j * 8];
}

// ---------------- GEMM: C[M][N] = A[M][K] @ Bt[N][K]^T (m97 structure) ----------------
template <int F32OUT>
__global__ __launch_bounds__(256, 2) void gemm_bt(const _Float16* __restrict__ A,
                                                  const _Float16* __restrict__ Bt,
                                                  void* __restrict__ Cp,
                                                  int M, int N, int K) {
  __shared__ _Float16 As[128 * 32];
  __shared__ _Float16 Bs[128 * 32];
  const int nbn = N >> 7;
  const int bm = blockIdx.x / nbn, bn = blockIdx.x % nbn;
  const int t = threadIdx.x, w = t >> 6, l = t & 63;
  const int lr = l & 15, lg = l >> 4;
  const int wr = w >> 1, wc = w & 1;
  const int m0 = bm << 7, n0 = bn << 7;

  f32x4 acc[4][4] = {};

  for (int k0 = 0; k0 < K; k0 += 32) {
#pragma unroll
    for (int p = 0; p < 2; ++p) {
      int off = p * 4096 + w * 1024 + l * 16;  // linear byte offset in 8KB tile
      int row = off >> 6;                       // 64B per row (32 f16)
      int col = (off & 63) >> 1;                // element col
      gload_lds16(A  + (size_t)(m0 + row) * K + k0 + col, (char*)As + p * 4096 + w * 1024);
      gload_lds16(Bt + (size_t)(n0 + row) * K + k0 + col, (char*)Bs + p * 4096 + w * 1024);
    }
    __syncthreads();
    f16x8 af[4], bq[4];
#pragma unroll
    for (int i = 0; i < 4; ++i) {
      af[i] = *(const f16x8*)((const char*)As + (wr * 64 + i * 16 + lr) * 64 + lg * 16);
      bq[i] = *(const f16x8*)((const char*)Bs + (wc * 64 + i * 16 + lr) * 64 + lg * 16);
    }
#pragma unroll
    for (int i = 0; i < 4; ++i)
#pragma unroll
      for (int j = 0; j < 4; ++j)
        acc[i][j] = __builtin_amdgcn_mfma_f32_16x16x32_f16(af[i], bq[j], acc[i][j], 0, 0, 0);
    __syncthreads();
  }
#pragma unroll
  for (int i = 0; i < 4; ++i)
#pragma unroll
    for (int j = 0; j < 4; ++j)
#pragma unroll
      for (int r = 0; r < 4; ++r) {
        size_t row = m0 + wr * 64 + i * 16 + lg * 4 + r;
        size_t col = n0 + wc * 64 + j * 16 + lr;
        if (F32OUT) ((float*)Cp)[row * N + col] = acc[i][j][r];
        else ((_Float16*)Cp)[row * N + col] = (_Float16)acc[i][j][r];
      }
}

// ---------------- V [b][kv][1024+h*64+d] -> Vt [b][h][d][kv] ----------------
__global__ __launch_bounds__(256) void vtrans(const _Float16* __restrict__ KVb,
                                              _Float16* __restrict__ Vt) {
  __shared__ _Float16 tile[64][72];  // [kv][d], padded rows (144B, 16B-aligned)
  int idx = blockIdx.x;
  int kt = idx & 31, h = (idx >> 5) & 15, b = idx >> 9;
  int kv0 = kt << 6;
  int t = threadIdx.x;
#pragma unroll
  for (int p = 0; p < 2; ++p) {
    int c = t + p * 256;
    int row = c >> 3, cb = (c & 7) * 16;
    f16x8 v = *(const f16x8*)(KVb + (size_t)(b * NKV_ + kv0 + row) * DKV_ + 1024 + h * 64 + cb / 2);
    *(f16x8*)((char*)&tile[row][0] + cb) = v;
  }
  __syncthreads();
  int d = t & 63, j0 = (t >> 6) * 2;
#pragma unroll
  for (int jj = 0; jj < 2; ++jj) {
    int kvs = (j0 + jj) * 8;
    f16x8 o;
#pragma unroll
    for (int u = 0; u < 8; ++u) o[u] = tile[kvs + u][d];
    *(f16x8*)(Vt + ((size_t)((b * H_ + h) * 64 + d)) * NKV_ + kv0 + kvs) = o;
  }
}

// ---------------- fused attention: softmax(Q K^T + bias) V ----------------
// Round-7 swapped-operand core (16x16 MFMA, q lane-local softmax, defer-max,
// exp2 domain) + KVBLK=128 (2 inner halves per staging phase, half the
// barriers) + 256B-row Vs (conflict-free V reads) + XCD swizzle grouping the
// 4 batches of one (h,qt) on the same XCD for bias L2 reuse.
__global__ __launch_bounds__(256, 4) void attn(const _Float16* __restrict__ Qb,
                                               const _Float16* __restrict__ KVb,
                                               const _Float16* __restrict__ Vt,
                                               const float* __restrict__ bias,
                                               _Float16* __restrict__ ctx) {
  __shared__ _Float16 Ks[128 * 64];     // [kv 0..127][d 0..63], 128B rows, XOR-swizzled
  __shared__ _Float16 Vs[64 * 128];     // [d 0..63][kv 0..127], 256B rows, XOR-swizzled
  __shared__ _Float16 Ps[4][16 * 64];   // per-wave P^T as [q][kv 64], XOR-swizzled
  const float LOG2E = 1.44269504f;
  // XCD-bijective decode: idx = (hq&7) + 8*(b + 4*(hq>>3)), hq = h*32+qt.
  int idx = blockIdx.x;
  int xr = idx & 7, m = idx >> 3;
  int b = m & 3;
  int hq = (m >> 2) * 8 + xr;
  int hd = hq >> 5, qt = hq & 31;
  int t = threadIdx.x, w = t >> 6, l = t & 63, lr = l & 15, lg = l >> 4;
  int qw = (qt << 6) + (w << 4);

  const _Float16* qp = Qb + (size_t)(b * NQ_ + qw + lr) * DM_ + hd * 64 + lg * 8;
  f16x8 aq0 = *(const f16x8*)qp;
  f16x8 aq1 = *(const f16x8*)(qp + 32);
  // pre-scale Q by log2(e): QK^T lands directly in exp2 domain
#pragma unroll
  for (int u = 0; u < 8; ++u) { aq0[u] = aq0[u] * (_Float16)LOG2E; aq1[u] = aq1[u] * (_Float16)LOG2E; }

  f32x4 acc[4] = {};          // acc^T: [d-tile nt][r], d = nt*16+lg*4+r, q = lr
  float mrow = -1e30f;        // running max for q = qw+lr (exp2 domain)
  float lsum = 0.f;

  const _Float16* Kbase = KVb + (size_t)b * NKV_ * DKV_ + hd * 64;
  const _Float16* Vtb   = Vt + (size_t)(b * H_ + hd) * 64 * NKV_;
  const float*    biasq = bias + ((size_t)hd * NQ_ + qw + lr) * NKV_ + lg * 4;  // per-lane q row

  // K staging: rows t>>3 (+32p), 16B col (t&7)*16.  V staging: rows t>>4 (+16p), 16B col (t&15)*16.
  const int ksrow = t >> 3, kscb = (t & 7) * 16;
  const int vsrow = t >> 4, vscb = (t & 15) * 16;

  f16x8 kreg[4], vreg[4];

  auto LOADKV = [&](int kv0) {
#pragma unroll
    for (int p = 0; p < 4; ++p) {
      kreg[p] = *(const f16x8*)(Kbase + (size_t)(kv0 + ksrow + p * 32) * DKV_ + kscb / 2);
      vreg[p] = *(const f16x8*)(Vtb + (size_t)(vsrow + p * 16) * NKV_ + kv0 + vscb / 2);
    }
  };

  // prologue: tile0 -> regs
  LOADKV(0);

  for (int it = 0; it < 16; ++it) {
    const int kv0 = it << 7;

    // ---- write staged regs (tile it, 128 kv) to LDS ----
#pragma unroll
    for (int p = 0; p < 4; ++p) {
      int krow = ksrow + p * 32;
      *(f16x8*)((char*)Ks + ((krow * 128 + kscb) ^ ((krow & 7) << 4))) = kreg[p];
      int vrow = vsrow + p * 16;
      *(f16x8*)((char*)Vs + ((vrow * 256 + vscb) ^ ((vrow & 15) << 4))) = vreg[p];
    }
    __syncthreads();

    // ---- issue next tile's global loads (consumed next iteration) ----
    LOADKV((it < 15) ? kv0 + 128 : kv0);

    // ---- two inner 64-kv halves ----
#pragma unroll
    for (int T = 0; T < 2; ++T) {
      const int kvh = kv0 + 64 * T;

      // bias loads (float4, contiguous kv per lane), cover under QK^T
      float4 bv4[4];
#pragma unroll
      for (int nt = 0; nt < 4; ++nt)
        bv4[nt] = *(const float4*)(biasq + kvh + nt * 16);

      // S^T = K Q^T: lane holds S[kv = nt*16+lg*4+r][q = lr]
      f32x4 s[4];
      __builtin_amdgcn_s_setprio(1);
#pragma unroll
      for (int nt = 0; nt < 4; ++nt) {
        int row = T * 64 + nt * 16 + lr;
        int sw = (row & 7) << 4;
        f16x8 kf0 = *(const f16x8*)((char*)Ks + ((row * 128 + lg * 16) ^ sw));
        f16x8 kf1 = *(const f16x8*)((char*)Ks + ((row * 128 + 64 + lg * 16) ^ sw));
        f32x4 z = {0.f, 0.f, 0.f, 0.f};
        z = __builtin_amdgcn_mfma_f32_16x16x32_f16(kf0, aq0, z, 0, 0, 0);
        s[nt] = __builtin_amdgcn_mfma_f32_16x16x32_f16(kf1, aq1, z, 0, 0, 0);
      }
      __builtin_amdgcn_s_setprio(0);

      // + bias (exp2 domain via fma)
#pragma unroll
      for (int nt = 0; nt < 4; ++nt) {
        s[nt][0] = fmaf(bv4[nt].x, LOG2E, s[nt][0]);
        s[nt][1] = fmaf(bv4[nt].y, LOG2E, s[nt][1]);
        s[nt][2] = fmaf(bv4[nt].z, LOG2E, s[nt][2]);
        s[nt][3] = fmaf(bv4[nt].w, LOG2E, s[nt][3]);
      }

      // row max: 15 in-lane + 2 shuffles (q-row is lane-local)
      float pmax = fmaxf(fmaxf(s[0][0], s[0][1]), fmaxf(s[0][2], s[0][3]));
#pragma unroll
      for (int nt = 1; nt < 4; ++nt)
        pmax = fmaxf(pmax, fmaxf(fmaxf(s[nt][0], s[nt][1]), fmaxf(s[nt][2], s[nt][3])));
      pmax = fmaxf(pmax, __shfl_xor(pmax, 16));
      pmax = fmaxf(pmax, __shfl_xor(pmax, 32));

      // defer-max: rescale only when max grew past THR=8 (P <= 2^8, f16-safe)
      if (__any(pmax > mrow + 8.0f)) {
        float mn = fmaxf(mrow, pmax);
        float corr = exp2f(mrow - mn);
        mrow = mn;
        lsum *= corr;
#pragma unroll
        for (int nt = 0; nt < 4; ++nt)
#pragma unroll
          for (int r = 0; r < 4; ++r) acc[nt][r] *= corr;
      }

      // P = exp2(S - mrow); row sum: 15 in-lane + 2 shuffles
      float rs = 0.f;
#pragma unroll
      for (int nt = 0; nt < 4; ++nt)
#pragma unroll
        for (int r = 0; r < 4; ++r) {
          float p = exp2f(s[nt][r] - mrow);
          s[nt][r] = p;
          rs += p;
        }
      rs += __shfl_xor(rs, 16);
      rs += __shfl_xor(rs, 32);
      lsum += rs;

      // P^T -> per-wave LDS [q][kv] as 4x f16x4 (8B) writes
#pragma unroll
      for (int nt = 0; nt < 4; ++nt) {
        f16x4 pk = {(_Float16)s[nt][0], (_Float16)s[nt][1],
                    (_Float16)s[nt][2], (_Float16)s[nt][3]};
        int off = (lr * 128 + nt * 32 + lg * 8) ^ ((lr & 7) << 4);
        *(f16x4*)((char*)Ps[w] + off) = pk;
      }

      // PV swapped: acc^T = mfma(V^T-frag, P^T-frag)
      __builtin_amdgcn_s_setprio(1);
#pragma unroll
      for (int kk = 0; kk < 2; ++kk) {
        f16x8 pb = *(const f16x8*)((char*)Ps[w] +
                   ((lr * 128 + kk * 64 + lg * 16) ^ ((lr & 7) << 4)));
#pragma unroll
        for (int nt = 0; nt < 4; ++nt) {
          int vrow = nt * 16 + lr;
          f16x8 vf = *(const f16x8*)((char*)Vs +
                   ((vrow * 256 + T * 128 + kk * 64 + lg * 16) ^ ((vrow & 15) << 4)));
          acc[nt] = __builtin_amdgcn_mfma_f32_16x16x32_f16(vf, pb, acc[nt], 0, 0, 0);
        }
      }
      __builtin_amdgcn_s_setprio(0);
    }
    __syncthreads();
  }

  // ---- normalize + write ctx[b][q=qw+lr][hd*64 + nt*16+lg*4+{0..3}] (8B stores) ----
  float inv = 1.0f / lsum;
#pragma unroll
  for (int nt = 0; nt < 4; ++nt) {
    f16x4 o = {(_Float16)(acc[nt][0] * inv), (_Float16)(acc[nt][1] * inv),
               (_Float16)(acc[nt][2] * inv), (_Float16)(acc[nt][3] * inv)};
    *(f16x4*)(ctx + ((size_t)b * NQ_ + qw + lr) * DM_ + hd * 64 + nt * 16 + lg * 4) = o;
  }
}

extern "C" void kernel_launch(void* const* d_in, const int* in_sizes, int n_in,
                              void* d_out, int out_size, void* d_ws, size_t ws_size,
                              hipStream_t stream) {
  const float* x    = (const float*)d_in[0];
  const float* enc  = (const float*)d_in[1];
  const float* bias = (const float*)d_in[2];
  const float* Wq   = (const float*)d_in[3];
  const float* Wk   = (const float*)d_in[4];
  const float* Wv   = (const float*)d_in[5];
  const float* Wo   = (const float*)d_in[6];
  char* ws = (char*)d_ws;
  const size_t MiB = 1024 * 1024;
  _Float16* WqT   = (_Float16*)(ws + 0 * MiB);
  _Float16* WkT   = (_Float16*)(ws + 2 * MiB);   // WkT+WvT contiguous: stacked Bt [2048][1024]
  _Float16* WvT   = (_Float16*)(ws + 4 * MiB);
  _Float16* WoT   = (_Float16*)(ws + 6 * MiB);
  _Float16* xf    = (_Float16*)(ws + 8 * MiB);
  _Float16* encf  = (_Float16*)(ws + 24 * MiB);
  _Float16* Qb    = (_Float16*)(ws + 40 * MiB);
  _Float16* KVb   = (_Float16*)(ws + 56 * MiB);  // [8192][2048]: cols 0..1023=K, 1024..2047=V
  _Float16* Vt    = (_Float16*)(ws + 88 * MiB);  // [B][H][64][NKV]
  _Float16* ctxf  = (_Float16*)(ws + 104 * MiB); // [8192][1024]

  wtrans<<<1024, 256, 0, stream>>>(Wq, WqT);
  wtrans<<<1024, 256, 0, stream>>>(Wk, WkT);
  wtrans<<<1024, 256, 0, stream>>>(Wv, WvT);
  wtrans<<<1024, 256, 0, stream>>>(Wo, WoT);
  cast_f16<<<8192, 256, 0, stream>>>(x, xf, 2097152);
  cast_f16<<<8192, 256, 0, stream>>>(enc, encf, 2097152);
  gemm_bt<0><<<512, 256, 0, stream>>>(xf, WqT, Qb, 8192, 1024, 1024);
  gemm_bt<0><<<1024, 256, 0, stream>>>(encf, WkT, KVb, 8192, 2048, 1024);
  vtrans<<<2048, 256, 0, stream>>>(KVb, Vt);
  attn<<<2048, 256, 0, stream>>>(Qb, KVb, Vt, bias, ctxf);
  gemm_bt<1><<<512, 256, 0, stream>>>(ctxf, WoT, d_out, 8192, 1024, 1024);
}

// Round 10
// 517.892 us; speedup vs baseline: 1.0490x; 1.0490x over previous
//
#include <hip/hip_runtime.h>

// Problem constants
#define B_   4
#define NQ_  2048
#define NKV_ 2048
#define H_   16
#define DK_  64
#define DM_  1024
#define DKV_ 2048   // stacked K|V projection width

typedef _Float16 f16x8 __attribute__((ext_vector_type(8)));
typedef _Float16 f16x4 __attribute__((ext_vector_type(4)));
typedef float    f32x4 __attribute__((ext_vector_type(4)));

__device__ __forceinline__ void gload_lds16(const void* g, void* l) {
  __builtin_amdgcn_global_load_lds(
      (const __attribute__((address_space(1))) unsigned int*)g,
      (__attribute__((address_space(3))) unsigned int*)l, 16, 0, 0);
}

// ---------------- cast f32 -> f16 (4 elems/thread) ----------------
__global__ __launch_bounds__(256) void cast_f16(const float* __restrict__ in,
                                                _Float16* __restrict__ out, int n4) {
  int i = blockIdx.x * 256 + threadIdx.x;
  if (i >= n4) return;
  float4 v = ((const float4*)in)[i];
  f16x4 o = {(_Float16)v.x, (_Float16)v.y, (_Float16)v.z, (_Float16)v.w};
  *(f16x4*)(out + (size_t)i * 4) = o;
}

// ---------------- W [K][N] f32 -> Wt [N][K] f16 ----------------
__global__ __launch_bounds__(256) void wtrans(const float* __restrict__ W,
                                              _Float16* __restrict__ Wt) {
  __shared__ float tile[32][33];
  int bx = blockIdx.x & 31, by = blockIdx.x >> 5;
  int tx = threadIdx.x & 31, ty = threadIdx.x >> 5;  // ty 0..7
#pragma unroll
  for (int j = 0; j < 4; ++j)
    tile[ty + j * 8][tx] = W[(size_t)(by * 32 + ty + j * 8) * 1024 + bx * 32 + tx];
  __syncthreads();
#pragma unroll
  for (int j = 0; j < 4; ++j)
    Wt[(size_t)(bx * 32 + ty + j * 8) * 1024 + by * 32 + tx] = (_Float16)tile[tx][ty + j * 8];
}

// ---------------- GEMM: C[M][N] = A[M][K] @ Bt[N][K]^T (m97 structure) ----------------
template <int F32OUT>
__global__ __launch_bounds__(256, 2) void gemm_bt(const _Float16* __restrict__ A,
                                                  const _Float16* __restrict__ Bt,
                                                  void* __restrict__ Cp,
                                                  int M, int N, int K) {
  __shared__ _Float16 As[128 * 32];
  __shared__ _Float16 Bs[128 * 32];
  const int nbn = N >> 7;
  const int bm = blockIdx.x / nbn, bn = blockIdx.x % nbn;
  const int t = threadIdx.x, w = t >> 6, l = t & 63;
  const int lr = l & 15, lg = l >> 4;
  const int wr = w >> 1, wc = w & 1;
  const int m0 = bm << 7, n0 = bn << 7;

  f32x4 acc[4][4] = {};

  for (int k0 = 0; k0 < K; k0 += 32) {
#pragma unroll
    for (int p = 0; p < 2; ++p) {
      int off = p * 4096 + w * 1024 + l * 16;  // linear byte offset in 8KB tile
      int row = off >> 6;                       // 64B per row (32 f16)
      int col = (off & 63) >> 1;                // element col
      gload_lds16(A  + (size_t)(m0 + row) * K + k0 + col, (char*)As + p * 4096 + w * 1024);
      gload_lds16(Bt + (size_t)(n0 + row) * K + k0 + col, (char*)Bs + p * 4096 + w * 1024);
    }
    __syncthreads();
    f16x8 af[4], bq[4];
#pragma unroll
    for (int i = 0; i < 4; ++i) {
      af[i] = *(const f16x8*)((const char*)As + (wr * 64 + i * 16 + lr) * 64 + lg * 16);
      bq[i] = *(const f16x8*)((const char*)Bs + (wc * 64 + i * 16 + lr) * 64 + lg * 16);
    }
#pragma unroll
    for (int i = 0; i < 4; ++i)
#pragma unroll
      for (int j = 0; j < 4; ++j)
        acc[i][j] = __builtin_amdgcn_mfma_f32_16x16x32_f16(af[i], bq[j], acc[i][j], 0, 0, 0);
    __syncthreads();
  }
#pragma unroll
  for (int i = 0; i < 4; ++i)
#pragma unroll
    for (int j = 0; j < 4; ++j)
#pragma unroll
      for (int r = 0; r < 4; ++r) {
        size_t row = m0 + wr * 64 + i * 16 + lg * 4 + r;
        size_t col = n0 + wc * 64 + j * 16 + lr;
        if (F32OUT) ((float*)Cp)[row * N + col] = acc[i][j][r];
        else ((_Float16*)Cp)[row * N + col] = (_Float16)acc[i][j][r];
      }
}

// ---------------- V [b][kv][1024+h*64+d] -> Vt [b][h][d][kv] ----------------
__global__ __launch_bounds__(256) void vtrans(const _Float16* __restrict__ KVb,
                                              _Float16* __restrict__ Vt) {
  __shared__ _Float16 tile[64][72];  // [kv][d], padded rows (144B, 16B-aligned)
  int idx = blockIdx.x;
  int kt = idx & 31, h = (idx >> 5) & 15, b = idx >> 9;
  int kv0 = kt << 6;
  int t = threadIdx.x;
#pragma unroll
  for (int p = 0; p < 2; ++p) {
    int c = t + p * 256;
    int row = c >> 3, cb = (c & 7) * 16;
    f16x8 v = *(const f16x8*)(KVb + (size_t)(b * NKV_ + kv0 + row) * DKV_ + 1024 + h * 64 + cb / 2);
    *(f16x8*)((char*)&tile[row][0] + cb) = v;
  }
  __syncthreads();
  int d = t & 63, j0 = (t >> 6) * 2;
#pragma unroll
  for (int jj = 0; jj < 2; ++jj) {
    int kvs = (j0 + jj) * 8;
    f16x8 o;
#pragma unroll
    for (int u = 0; u < 8; ++u) o[u] = tile[kvs + u][d];
    *(f16x8*)(Vt + ((size_t)((b * H_ + h) * 64 + d)) * NKV_ + kv0 + kvs) = o;
  }
}

// ---------------- fused attention: softmax(Q K^T + bias) V ----------------
// Round-7 swapped-operand core (16x16 MFMA, lane-local q softmax, defer-max,
// exp2 domain, single-buffer LDS, 2 barriers/iter, NO grid swizzle) with
// qe=2: each wave owns 32 q-rows -> K/V fragment reads, staging, barriers
// and global K/V traffic all amortized 2x per q-row. Grid 1024 = 4 blocks/CU.
__global__ __launch_bounds__(256, 4) void attn(const _Float16* __restrict__ Qb,
                                               const _Float16* __restrict__ KVb,
                                               const _Float16* __restrict__ Vt,
                                               const float* __restrict__ bias,
                                               _Float16* __restrict__ ctx) {
  __shared__ _Float16 Ks[64 * 64];      // [kv][d], XOR-swizzled rows
  __shared__ _Float16 Vs[64 * 64];      // [d][kv], XOR-swizzled rows
  __shared__ _Float16 Ps[4][32 * 64];   // per-wave P^T as [q 0..31][kv 64], swizzled
  const float LOG2E = 1.44269504f;
  int idx = blockIdx.x;
  int b = idx & 3, qt = (idx >> 2) & 15, hd = idx >> 6;  // batch innermost (L3-proven order)
  int t = threadIdx.x, w = t >> 6, l = t & 63, lr = l & 15, lg = l >> 4;
  int qw = (qt << 7) + (w << 5);   // wave's 32 q rows

  f16x8 aq[2][2];
#pragma unroll
  for (int qe = 0; qe < 2; ++qe) {
    const _Float16* qp = Qb + (size_t)(b * NQ_ + qw + qe * 16 + lr) * DM_ + hd * 64 + lg * 8;
    aq[qe][0] = *(const f16x8*)qp;
    aq[qe][1] = *(const f16x8*)(qp + 32);
#pragma unroll
    for (int u = 0; u < 8; ++u) {
      aq[qe][0][u] = aq[qe][0][u] * (_Float16)LOG2E;
      aq[qe][1][u] = aq[qe][1][u] * (_Float16)LOG2E;
    }
  }

  f32x4 acc[2][4] = {};       // acc^T per qe: [nt][r], d = nt*16+lg*4+r, q = qe*16+lr
  float mrow[2] = {-1e30f, -1e30f};
  float lsum[2] = {0.f, 0.f};

  const _Float16* Kbase = KVb + (size_t)b * NKV_ * DKV_ + hd * 64;
  const _Float16* Vtb   = Vt + (size_t)(b * H_ + hd) * 64 * NKV_;
  const float*    biasq = bias + ((size_t)hd * NQ_ + qw + lr) * NKV_ + lg * 4;  // qe adds 16*NKV

  const int srow = t >> 3;        // staging row (p adds 32)
  const int scb  = (t & 7) * 16;  // staging byte col within 128B row

  f16x8 kreg[2], vreg[2];

  auto LOADKV = [&](int kv0) {
#pragma unroll
    for (int p = 0; p < 2; ++p) {
      int row = srow + p * 32;
      kreg[p] = *(const f16x8*)(Kbase + (size_t)(kv0 + row) * DKV_ + scb / 2);
      vreg[p] = *(const f16x8*)(Vtb + (size_t)row * NKV_ + kv0 + scb / 2);
    }
  };

  // prologue: tile0 -> regs
  LOADKV(0);

  for (int it = 0; it < 32; ++it) {
    const int kv0 = it << 6;

    // ---- write staged regs (tile it) to LDS ----
#pragma unroll
    for (int p = 0; p < 2; ++p) {
      int row = srow + p * 32;
      int off = (row * 128 + scb) ^ ((row & 7) << 4);
      *(f16x8*)((char*)Ks + off) = kreg[p];
      *(f16x8*)((char*)Vs + off) = vreg[p];
    }
    __syncthreads();

    // ---- bias for qe=0 issues before the MFMA cluster (latency covered) ----
    float4 bv0[4];
#pragma unroll
    for (int nt = 0; nt < 4; ++nt)
      bv0[nt] = *(const float4*)(biasq + kv0 + nt * 16);

    // ---- S^T = K Q^T for both q-tiles, K-frags loaded once ----
    f32x4 s[2][4];
    __builtin_amdgcn_s_setprio(1);
#pragma unroll
    for (int nt = 0; nt < 4; ++nt) {
      int row = nt * 16 + lr;
      int sw = (row & 7) << 4;
      f16x8 kf0 = *(const f16x8*)((char*)Ks + ((row * 128 + lg * 16) ^ sw));
      f16x8 kf1 = *(const f16x8*)((char*)Ks + ((row * 128 + 64 + lg * 16) ^ sw));
#pragma unroll
      for (int qe = 0; qe < 2; ++qe) {
        f32x4 z = {0.f, 0.f, 0.f, 0.f};
        z = __builtin_amdgcn_mfma_f32_16x16x32_f16(kf0, aq[qe][0], z, 0, 0, 0);
        s[qe][nt] = __builtin_amdgcn_mfma_f32_16x16x32_f16(kf1, aq[qe][1], z, 0, 0, 0);
      }
    }
    __builtin_amdgcn_s_setprio(0);

    // ---- issue next tile's global loads (covered by softmax + PV) ----
    LOADKV((it < 31) ? kv0 + 64 : kv0);

    // ---- per-qe softmax (qe=1 bias issues during qe=0 softmax) ----
    float4 bv1[4];
#pragma unroll
    for (int nt = 0; nt < 4; ++nt)
      bv1[nt] = *(const float4*)(biasq + 16 * NKV_ + kv0 + nt * 16);

#pragma unroll
    for (int qe = 0; qe < 2; ++qe) {
      float4* bv = qe ? bv1 : bv0;
      // + bias (exp2 domain via fma)
#pragma unroll
      for (int nt = 0; nt < 4; ++nt) {
        s[qe][nt][0] = fmaf(bv[nt].x, LOG2E, s[qe][nt][0]);
        s[qe][nt][1] = fmaf(bv[nt].y, LOG2E, s[qe][nt][1]);
        s[qe][nt][2] = fmaf(bv[nt].z, LOG2E, s[qe][nt][2]);
        s[qe][nt][3] = fmaf(bv[nt].w, LOG2E, s[qe][nt][3]);
      }

      // row max: 15 in-lane + 2 shuffles (q lane-local)
      float pmax = fmaxf(fmaxf(s[qe][0][0], s[qe][0][1]), fmaxf(s[qe][0][2], s[qe][0][3]));
#pragma unroll
      for (int nt = 1; nt < 4; ++nt)
        pmax = fmaxf(pmax, fmaxf(fmaxf(s[qe][nt][0], s[qe][nt][1]),
                                 fmaxf(s[qe][nt][2], s[qe][nt][3])));
      pmax = fmaxf(pmax, __shfl_xor(pmax, 16));
      pmax = fmaxf(pmax, __shfl_xor(pmax, 32));

      // defer-max: rescale only when max grew past THR=8 (P <= 2^8, f16-safe)
      if (__any(pmax > mrow[qe] + 8.0f)) {
        float mn = fmaxf(mrow[qe], pmax);
        float corr = exp2f(mrow[qe] - mn);
        mrow[qe] = mn;
        lsum[qe] *= corr;
#pragma unroll
        for (int nt = 0; nt < 4; ++nt)
#pragma unroll
          for (int r = 0; r < 4; ++r) acc[qe][nt][r] *= corr;
      }

      // P = exp2(S - mrow); row sum: 15 in-lane + 2 shuffles
      float rs = 0.f;
#pragma unroll
      for (int nt = 0; nt < 4; ++nt)
#pragma unroll
        for (int r = 0; r < 4; ++r) {
          float p = exp2f(s[qe][nt][r] - mrow[qe]);
          s[qe][nt][r] = p;
          rs += p;
        }
      rs += __shfl_xor(rs, 16);
      rs += __shfl_xor(rs, 32);
      lsum[qe] += rs;

      // P^T -> per-wave LDS [q = qe*16+lr][kv] as 4x f16x4 (8B) writes
      const int prow = qe * 16 + lr;
#pragma unroll
      for (int nt = 0; nt < 4; ++nt) {
        f16x4 pk = {(_Float16)s[qe][nt][0], (_Float16)s[qe][nt][1],
                    (_Float16)s[qe][nt][2], (_Float16)s[qe][nt][3]};
        int off = (prow * 128 + nt * 32 + lg * 8) ^ ((lr & 7) << 4);
        *(f16x4*)((char*)Ps[w] + off) = pk;
      }
    }

    // ---- PV swapped: acc^T = mfma(V^T-frag, P^T-frag); vf shared across qe ----
    __builtin_amdgcn_s_setprio(1);
#pragma unroll
    for (int kk = 0; kk < 2; ++kk) {
      f16x8 pb[2];
#pragma unroll
      for (int qe = 0; qe < 2; ++qe) {
        int prow = qe * 16 + lr;
        pb[qe] = *(const f16x8*)((char*)Ps[w] +
                 ((prow * 128 + kk * 64 + lg * 16) ^ ((lr & 7) << 4)));
      }
#pragma unroll
      for (int nt = 0; nt < 4; ++nt) {
        int vrow = nt * 16 + lr;
        f16x8 vf = *(const f16x8*)((char*)Vs +
                 ((vrow * 128 + kk * 64 + lg * 16) ^ ((vrow & 7) << 4)));
#pragma unroll
        for (int qe = 0; qe < 2; ++qe)
          acc[qe][nt] = __builtin_amdgcn_mfma_f32_16x16x32_f16(vf, pb[qe], acc[qe][nt], 0, 0, 0);
      }
    }
    __builtin_amdgcn_s_setprio(0);
    __syncthreads();
  }

  // ---- normalize + write ctx[b][q][hd*64 + nt*16+lg*4+{0..3}] (8B stores) ----
#pragma unroll
  for (int qe = 0; qe < 2; ++qe) {
    float inv = 1.0f / lsum[qe];
#pragma unroll
    for (int nt = 0; nt < 4; ++nt) {
      f16x4 o = {(_Float16)(acc[qe][nt][0] * inv), (_Float16)(acc[qe][nt][1] * inv),
                 (_Float16)(acc[qe][nt][2] * inv), (_Float16)(acc[qe][nt][3] * inv)};
      *(f16x4*)(ctx + ((size_t)b * NQ_ + qw + qe * 16 + lr) * DM_ + hd * 64 + nt * 16 + lg * 4) = o;
    }
  }
}

extern "C" void kernel_launch(void* const* d_in, const int* in_sizes, int n_in,
                              void* d_out, int out_size, void* d_ws, size_t ws_size,
                              hipStream_t stream) {
  const float* x    = (const float*)d_in[0];
  const float* enc  = (const float*)d_in[1];
  const float* bias = (const float*)d_in[2];
  const float* Wq   = (const float*)d_in[3];
  const float* Wk   = (const float*)d_in[4];
  const float* Wv   = (const float*)d_in[5];
  const float* Wo   = (const float*)d_in[6];
  char* ws = (char*)d_ws;
  const size_t MiB = 1024 * 1024;
  _Float16* WqT   = (_Float16*)(ws + 0 * MiB);
  _Float16* WkT   = (_Float16*)(ws + 2 * MiB);   // WkT+WvT contiguous: stacked Bt [2048][1024]
  _Float16* WvT   = (_Float16*)(ws + 4 * MiB);
  _Float16* WoT   = (_Float16*)(ws + 6 * MiB);
  _Float16* xf    = (_Float16*)(ws + 8 * MiB);
  _Float16* encf  = (_Float16*)(ws + 24 * MiB);
  _Float16* Qb    = (_Float16*)(ws + 40 * MiB);
  _Float16* KVb   = (_Float16*)(ws + 56 * MiB);  // [8192][2048]: cols 0..1023=K, 1024..2047=V
  _Float16* Vt    = (_Float16*)(ws + 88 * MiB);  // [B][H][64][NKV]
  _Float16* ctxf  = (_Float16*)(ws + 104 * MiB); // [8192][1024]

  wtrans<<<1024, 256, 0, stream>>>(Wq, WqT);
  wtrans<<<1024, 256, 0, stream>>>(Wk, WkT);
  wtrans<<<1024, 256, 0, stream>>>(Wv, WvT);
  wtrans<<<1024, 256, 0, stream>>>(Wo, WoT);
  cast_f16<<<8192, 256, 0, stream>>>(x, xf, 2097152);
  cast_f16<<<8192, 256, 0, stream>>>(enc, encf, 2097152);
  gemm_bt<0><<<512, 256, 0, stream>>>(xf, WqT, Qb, 8192, 1024, 1024);
  gemm_bt<0><<<1024, 256, 0, stream>>>(encf, WkT, KVb, 8192, 2048, 1024);
  vtrans<<<2048, 256, 0, stream>>>(KVb, Vt);
  attn<<<1024, 256, 0, stream>>>(Qb, KVb, Vt, bias, ctxf);
  gemm_bt<1><<<512, 256, 0, stream>>>(ctxf, WoT, d_out, 8192, 1024, 1024);
}

// Round 11
// 350.458 us; speedup vs baseline: 1.5502x; 1.4778x over previous
//
#include <hip/hip_runtime.h>

// Problem constants
#define B_   4
#define NQ_  2048
#define NKV_ 2048
#define H_   16
#define DK_  64
#define DM_  1024
#define DKV_ 2048   // stacked K|V projection width

typedef _Float16 f16x8 __attribute__((ext_vector_type(8)));
typedef _Float16 f16x4 __attribute__((ext_vector_type(4)));
typedef float    f32x4 __attribute__((ext_vector_type(4)));

__device__ __forceinline__ void gload_lds16(const void* g, void* l) {
  __builtin_amdgcn_global_load_lds(
      (const __attribute__((address_space(1))) unsigned int*)g,
      (__attribute__((address_space(3))) unsigned int*)l, 16, 0, 0);
}

// ---------------- cast f32 -> f16 for x and enc in one launch ----------------
__global__ __launch_bounds__(256) void cast2_f16(const float* __restrict__ a,
                                                 const float* __restrict__ b,
                                                 _Float16* __restrict__ ao,
                                                 _Float16* __restrict__ bo) {
  int i = blockIdx.x * 256 + threadIdx.x;       // 4M float4 total (2M each)
  const float* in = (i < 2097152) ? a : b;
  _Float16* out = (i < 2097152) ? ao : bo;
  int j = i & 2097151;
  float4 v = ((const float4*)in)[j];
  f16x4 o = {(_Float16)v.x, (_Float16)v.y, (_Float16)v.z, (_Float16)v.w};
  *(f16x4*)(out + (size_t)j * 4) = o;
}

// ---------------- all 4 weights: W [K][N] f32 -> Wt [N][K] f16, one launch ----------------
__global__ __launch_bounds__(256) void wtrans4(const float* __restrict__ Wq,
                                               const float* __restrict__ Wk,
                                               const float* __restrict__ Wv,
                                               const float* __restrict__ Wo,
                                               _Float16* __restrict__ WqT,
                                               _Float16* __restrict__ WkT,
                                               _Float16* __restrict__ WvT,
                                               _Float16* __restrict__ WoT) {
  __shared__ float tile[32][33];
  int which = blockIdx.x >> 10;
  const float* W = (which == 0) ? Wq : (which == 1) ? Wk : (which == 2) ? Wv : Wo;
  _Float16* Wt   = (which == 0) ? WqT : (which == 1) ? WkT : (which == 2) ? WvT : WoT;
  int idx = blockIdx.x & 1023;
  int bx = idx & 31, by = idx >> 5;
  int tx = threadIdx.x & 31, ty = threadIdx.x >> 5;  // ty 0..7
#pragma unroll
  for (int j = 0; j < 4; ++j)
    tile[ty + j * 8][tx] = W[(size_t)(by * 32 + ty + j * 8) * 1024 + bx * 32 + tx];
  __syncthreads();
#pragma unroll
  for (int j = 0; j < 4; ++j)
    Wt[(size_t)(bx * 32 + ty + j * 8) * 1024 + by * 32 + tx] = (_Float16)tile[tx][ty + j * 8];
}

// ---------------- GEMM: C[M][N] = A[M][K] @ Bt[N][K]^T (m97 structure) ----------------
template <int F32OUT>
__global__ __launch_bounds__(256, 2) void gemm_bt(const _Float16* __restrict__ A,
                                                  const _Float16* __restrict__ Bt,
                                                  void* __restrict__ Cp,
                                                  int M, int N, int K) {
  __shared__ _Float16 As[128 * 32];
  __shared__ _Float16 Bs[128 * 32];
  const int nbn = N >> 7;
  const int bm = blockIdx.x / nbn, bn = blockIdx.x % nbn;
  const int t = threadIdx.x, w = t >> 6, l = t & 63;
  const int lr = l & 15, lg = l >> 4;
  const int wr = w >> 1, wc = w & 1;
  const int m0 = bm << 7, n0 = bn << 7;

  f32x4 acc[4][4] = {};

  for (int k0 = 0; k0 < K; k0 += 32) {
#pragma unroll
    for (int p = 0; p < 2; ++p) {
      int off = p * 4096 + w * 1024 + l * 16;  // linear byte offset in 8KB tile
      int row = off >> 6;                       // 64B per row (32 f16)
      int col = (off & 63) >> 1;                // element col
      gload_lds16(A  + (size_t)(m0 + row) * K + k0 + col, (char*)As + p * 4096 + w * 1024);
      gload_lds16(Bt + (size_t)(n0 + row) * K + k0 + col, (char*)Bs + p * 4096 + w * 1024);
    }
    __syncthreads();
    f16x8 af[4], bq[4];
#pragma unroll
    for (int i = 0; i < 4; ++i) {
      af[i] = *(const f16x8*)((const char*)As + (wr * 64 + i * 16 + lr) * 64 + lg * 16);
      bq[i] = *(const f16x8*)((const char*)Bs + (wc * 64 + i * 16 + lr) * 64 + lg * 16);
    }
#pragma unroll
    for (int i = 0; i < 4; ++i)
#pragma unroll
      for (int j = 0; j < 4; ++j)
        acc[i][j] = __builtin_amdgcn_mfma_f32_16x16x32_f16(af[i], bq[j], acc[i][j], 0, 0, 0);
    __syncthreads();
  }
#pragma unroll
  for (int i = 0; i < 4; ++i)
#pragma unroll
    for (int j = 0; j < 4; ++j)
#pragma unroll
      for (int r = 0; r < 4; ++r) {
        size_t row = m0 + wr * 64 + i * 16 + lg * 4 + r;
        size_t col = n0 + wc * 64 + j * 16 + lr;
        if (F32OUT) ((float*)Cp)[row * N + col] = acc[i][j][r];
        else ((_Float16*)Cp)[row * N + col] = (_Float16)acc[i][j][r];
      }
}

// ---------------- V [b][kv][1024+h*64+d] -> Vt [b][h][d][kv] ----------------
__global__ __launch_bounds__(256) void vtrans(const _Float16* __restrict__ KVb,
                                              _Float16* __restrict__ Vt) {
  __shared__ _Float16 tile[64][72];  // [kv][d], padded rows (144B, 16B-aligned)
  int idx = blockIdx.x;
  int kt = idx & 31, h = (idx >> 5) & 15, b = idx >> 9;
  int kv0 = kt << 6;
  int t = threadIdx.x;
#pragma unroll
  for (int p = 0; p < 2; ++p) {
    int c = t + p * 256;
    int row = c >> 3, cb = (c & 7) * 16;
    f16x8 v = *(const f16x8*)(KVb + (size_t)(b * NKV_ + kv0 + row) * DKV_ + 1024 + h * 64 + cb / 2);
    *(f16x8*)((char*)&tile[row][0] + cb) = v;
  }
  __syncthreads();
  int d = t & 63, j0 = (t >> 6) * 2;
#pragma unroll
  for (int jj = 0; jj < 2; ++jj) {
    int kvs = (j0 + jj) * 8;
    f16x8 o;
#pragma unroll
    for (int u = 0; u < 8; ++u) o[u] = tile[kvs + u][d];
    *(f16x8*)(Vt + ((size_t)((b * H_ + h) * 64 + d)) * NKV_ + kv0 + kvs) = o;
  }
}

// ---------------- fused attention: softmax(Q K^T + bias) V ----------------
// EXACT round-7 core (16x16 swapped-operand MFMA, lane-local q softmax,
// defer-max, exp2 domain, no grid swizzle) with DOUBLE-BUFFERED K/V LDS:
// 2-unrolled loop, compile-time buffer pointers (full alias disambiguation),
// ONE barrier per KV-tile. LDS 40KB -> 4 blocks/CU at (256,4).
__global__ __launch_bounds__(256, 4) void attn(const _Float16* __restrict__ Qb,
                                               const _Float16* __restrict__ KVb,
                                               const _Float16* __restrict__ Vt,
                                               const float* __restrict__ bias,
                                               _Float16* __restrict__ ctx) {
  __shared__ _Float16 Ks0[64 * 64];     // [kv][d], XOR-swizzled rows
  __shared__ _Float16 Ks1[64 * 64];
  __shared__ _Float16 Vs0[64 * 64];     // [d][kv], XOR-swizzled rows
  __shared__ _Float16 Vs1[64 * 64];
  __shared__ _Float16 Ps[4][16 * 64];   // per-wave P^T as [q][kv], XOR-swizzled
  const float LOG2E = 1.44269504f;
  int idx = blockIdx.x;
  int b = idx & 3, qt = (idx >> 2) & 31, hd = idx >> 7;  // batch innermost (L3-proven order)
  int t = threadIdx.x, w = t >> 6, l = t & 63, lr = l & 15, lg = l >> 4;
  int qw = (qt << 6) + (w << 4);

  const _Float16* qp = Qb + (size_t)(b * NQ_ + qw + lr) * DM_ + hd * 64 + lg * 8;
  f16x8 aq0 = *(const f16x8*)qp;
  f16x8 aq1 = *(const f16x8*)(qp + 32);
  // pre-scale Q by log2(e): QK^T lands directly in exp2 domain
#pragma unroll
  for (int u = 0; u < 8; ++u) { aq0[u] = aq0[u] * (_Float16)LOG2E; aq1[u] = aq1[u] * (_Float16)LOG2E; }

  f32x4 acc[4] = {};          // acc^T: [d-tile nt][r], d = nt*16+lg*4+r, q = lr
  float mrow = -1e30f;        // running max for q = qw+lr (exp2 domain)
  float lsum = 0.f;

  const _Float16* Kbase = KVb + (size_t)b * NKV_ * DKV_ + hd * 64;
  const _Float16* Vtb   = Vt + (size_t)(b * H_ + hd) * 64 * NKV_;
  const float*    biasq = bias + ((size_t)hd * NQ_ + qw + lr) * NKV_ + lg * 4;  // per-lane q row

  const int srow = t >> 3;        // staging row (p adds 32)
  const int scb  = (t & 7) * 16;  // staging byte col within 128B row

  f16x8 kreg[2], vreg[2];

  auto LOADKV = [&](int kv0) {
#pragma unroll
    for (int p = 0; p < 2; ++p) {
      int row = srow + p * 32;
      kreg[p] = *(const f16x8*)(Kbase + (size_t)(kv0 + row) * DKV_ + scb / 2);
      vreg[p] = *(const f16x8*)(Vtb + (size_t)row * NKV_ + kv0 + scb / 2);
    }
  };
  auto WRITEKV = [&](_Float16* KsW, _Float16* VsW) {
#pragma unroll
    for (int p = 0; p < 2; ++p) {
      int row = srow + p * 32;
      int off = (row * 128 + scb) ^ ((row & 7) << 4);
      *(f16x8*)((char*)KsW + off) = kreg[p];
      *(f16x8*)((char*)VsW + off) = vreg[p];
    }
  };

  // body for one 64-kv tile: read from (KsR,VsR), stage next-next tile,
  // write staged regs (tile it+1) into (KsW,VsW). ONE barrier at the end.
  auto BODY = [&](const _Float16* KsR, const _Float16* VsR,
                  _Float16* KsW, _Float16* VsW, int it) {
    const int kv0 = it << 6;

    // ---- write staged regs (tile it+1) into the alternate buffer ----
    WRITEKV(KsW, VsW);

    // ---- issue tile it+2 global loads (consumed next iteration) ----
    int kvn = kv0 + 128;
    if (kvn > NKV_ - 64) kvn = NKV_ - 64;
    LOADKV(kvn);

    // ---- bias loads (float4, contiguous kv per lane), cover under QK^T ----
    float4 bv4[4];
#pragma unroll
    for (int nt = 0; nt < 4; ++nt)
      bv4[nt] = *(const float4*)(biasq + kv0 + nt * 16);

    // ---- S^T = K Q^T: lane holds S[kv = nt*16+lg*4+r][q = lr] ----
    f32x4 s[4];
    __builtin_amdgcn_s_setprio(1);
#pragma unroll
    for (int nt = 0; nt < 4; ++nt) {
      int row = nt * 16 + lr;
      int sw = (row & 7) << 4;
      f16x8 kf0 = *(const f16x8*)((const char*)KsR + ((row * 128 + lg * 16) ^ sw));
      f16x8 kf1 = *(const f16x8*)((const char*)KsR + ((row * 128 + 64 + lg * 16) ^ sw));
      f32x4 z = {0.f, 0.f, 0.f, 0.f};
      z = __builtin_amdgcn_mfma_f32_16x16x32_f16(kf0, aq0, z, 0, 0, 0);
      s[nt] = __builtin_amdgcn_mfma_f32_16x16x32_f16(kf1, aq1, z, 0, 0, 0);
    }
    __builtin_amdgcn_s_setprio(0);

    // ---- + bias (exp2 domain via fma) ----
#pragma unroll
    for (int nt = 0; nt < 4; ++nt) {
      s[nt][0] = fmaf(bv4[nt].x, LOG2E, s[nt][0]);
      s[nt][1] = fmaf(bv4[nt].y, LOG2E, s[nt][1]);
      s[nt][2] = fmaf(bv4[nt].z, LOG2E, s[nt][2]);
      s[nt][3] = fmaf(bv4[nt].w, LOG2E, s[nt][3]);
    }

    // ---- row max: 15 in-lane + 2 shuffles (q-row is lane-local) ----
    float pmax = fmaxf(fmaxf(s[0][0], s[0][1]), fmaxf(s[0][2], s[0][3]));
#pragma unroll
    for (int nt = 1; nt < 4; ++nt)
      pmax = fmaxf(pmax, fmaxf(fmaxf(s[nt][0], s[nt][1]), fmaxf(s[nt][2], s[nt][3])));
    pmax = fmaxf(pmax, __shfl_xor(pmax, 16));
    pmax = fmaxf(pmax, __shfl_xor(pmax, 32));

    // ---- defer-max: rescale only when max grew past THR=8 (P <= 2^8, f16-safe) ----
    if (__any(pmax > mrow + 8.0f)) {
      float mn = fmaxf(mrow, pmax);
      float corr = exp2f(mrow - mn);
      mrow = mn;
      lsum *= corr;
#pragma unroll
      for (int nt = 0; nt < 4; ++nt)
#pragma unroll
        for (int r = 0; r < 4; ++r) acc[nt][r] *= corr;
    }

    // ---- P = exp2(S - mrow); row sum: 15 in-lane + 2 shuffles ----
    float rs = 0.f;
#pragma unroll
    for (int nt = 0; nt < 4; ++nt)
#pragma unroll
      for (int r = 0; r < 4; ++r) {
        float p = exp2f(s[nt][r] - mrow);
        s[nt][r] = p;
        rs += p;
      }
    rs += __shfl_xor(rs, 16);
    rs += __shfl_xor(rs, 32);
    lsum += rs;

    // ---- P^T -> per-wave LDS [q][kv] as 4x f16x4 (8B) writes ----
#pragma unroll
    for (int nt = 0; nt < 4; ++nt) {
      f16x4 pk = {(_Float16)s[nt][0], (_Float16)s[nt][1],
                  (_Float16)s[nt][2], (_Float16)s[nt][3]};
      int off = (lr * 128 + nt * 32 + lg * 8) ^ ((lr & 7) << 4);
      *(f16x4*)((char*)Ps[w] + off) = pk;
    }

    // ---- PV swapped: acc^T = mfma(V^T-frag, P^T-frag) ----
    __builtin_amdgcn_s_setprio(1);
#pragma unroll
    for (int kk = 0; kk < 2; ++kk) {
      f16x8 pb = *(const f16x8*)((char*)Ps[w] +
                 ((lr * 128 + kk * 64 + lg * 16) ^ ((lr & 7) << 4)));
#pragma unroll
      for (int nt = 0; nt < 4; ++nt) {
        int row = nt * 16 + lr;
        f16x8 vf = *(const f16x8*)((const char*)VsR +
                 ((row * 128 + kk * 64 + lg * 16) ^ ((row & 7) << 4)));
        acc[nt] = __builtin_amdgcn_mfma_f32_16x16x32_f16(vf, pb, acc[nt], 0, 0, 0);
      }
    }
    __builtin_amdgcn_s_setprio(0);
    __syncthreads();  // tile it+1 writes visible; all reads of tile it done
  };

  // prologue: tile0 -> Ks0/Vs0; tile1 -> regs
  LOADKV(0);
  WRITEKV(Ks0, Vs0);
  LOADKV(64);
  __syncthreads();

  for (int i2 = 0; i2 < 16; ++i2) {
    BODY(Ks0, Vs0, Ks1, Vs1, i2 * 2);
    BODY(Ks1, Vs1, Ks0, Vs0, i2 * 2 + 1);
  }

  // ---- normalize + write ctx[b][q=qw+lr][hd*64 + nt*16+lg*4+{0..3}] (8B stores) ----
  float inv = 1.0f / lsum;
#pragma unroll
  for (int nt = 0; nt < 4; ++nt) {
    f16x4 o = {(_Float16)(acc[nt][0] * inv), (_Float16)(acc[nt][1] * inv),
               (_Float16)(acc[nt][2] * inv), (_Float16)(acc[nt][3] * inv)};
    *(f16x4*)(ctx + ((size_t)b * NQ_ + qw + lr) * DM_ + hd * 64 + nt * 16 + lg * 4) = o;
  }
}

extern "C" void kernel_launch(void* const* d_in, const int* in_sizes, int n_in,
                              void* d_out, int out_size, void* d_ws, size_t ws_size,
                              hipStream_t stream) {
  const float* x    = (const float*)d_in[0];
  const float* enc  = (const float*)d_in[1];
  const float* bias = (const float*)d_in[2];
  const float* Wq   = (const float*)d_in[3];
  const float* Wk   = (const float*)d_in[4];
  const float* Wv   = (const float*)d_in[5];
  const float* Wo   = (const float*)d_in[6];
  char* ws = (char*)d_ws;
  const size_t MiB = 1024 * 1024;
  _Float16* WqT   = (_Float16*)(ws + 0 * MiB);
  _Float16* WkT   = (_Float16*)(ws + 2 * MiB);   // WkT+WvT contiguous: stacked Bt [2048][1024]
  _Float16* WvT   = (_Float16*)(ws + 4 * MiB);
  _Float16* WoT   = (_Float16*)(ws + 6 * MiB);
  _Float16* xf    = (_Float16*)(ws + 8 * MiB);
  _Float16* encf  = (_Float16*)(ws + 24 * MiB);
  _Float16* Qb    = (_Float16*)(ws + 40 * MiB);
  _Float16* KVb   = (_Float16*)(ws + 56 * MiB);  // [8192][2048]: cols 0..1023=K, 1024..2047=V
  _Float16* Vt    = (_Float16*)(ws + 88 * MiB);  // [B][H][64][NKV]
  _Float16* ctxf  = (_Float16*)(ws + 104 * MiB); // [8192][1024]

  wtrans4<<<4096, 256, 0, stream>>>(Wq, Wk, Wv, Wo, WqT, WkT, WvT, WoT);
  cast2_f16<<<16384, 256, 0, stream>>>(x, enc, xf, encf);
  gemm_bt<0><<<512, 256, 0, stream>>>(xf, WqT, Qb, 8192, 1024, 1024);
  gemm_bt<0><<<1024, 256, 0, stream>>>(encf, WkT, KVb, 8192, 2048, 1024);
  vtrans<<<2048, 256, 0, stream>>>(KVb, Vt);
  attn<<<2048, 256, 0, stream>>>(Qb, KVb, Vt, bias, ctxf);
  gemm_bt<1><<<512, 256, 0, stream>>>(ctxf, WoT, d_out, 8192, 1024, 1024);
}

// Round 13
// 345.695 us; speedup vs baseline: 1.5716x; 1.0138x over previous
//
#include <hip/hip_runtime.h>

// Problem constants
#define B_   4
#define NQ_  2048
#define NKV_ 2048
#define H_   16
#define DK_  64
#define DM_  1024
#define DKV_ 2048   // stacked K|V projection width

typedef _Float16 f16x8 __attribute__((ext_vector_type(8)));
typedef _Float16 f16x4 __attribute__((ext_vector_type(4)));
typedef float    f32x4 __attribute__((ext_vector_type(4)));

__device__ __forceinline__ void gload_lds16(const void* g, void* l) {
  __builtin_amdgcn_global_load_lds(
      (const __attribute__((address_space(1))) unsigned int*)g,
      (__attribute__((address_space(3))) unsigned int*)l, 16, 0, 0);
}

// ---------------- cast f32 -> f16 for x and enc in one launch ----------------
__global__ __launch_bounds__(256) void cast2_f16(const float* __restrict__ a,
                                                 const float* __restrict__ b,
                                                 _Float16* __restrict__ ao,
                                                 _Float16* __restrict__ bo) {
  int i = blockIdx.x * 256 + threadIdx.x;       // 4M float4 total (2M each)
  const float* in = (i < 2097152) ? a : b;
  _Float16* out = (i < 2097152) ? ao : bo;
  int j = i & 2097151;
  float4 v = ((const float4*)in)[j];
  f16x4 o = {(_Float16)v.x, (_Float16)v.y, (_Float16)v.z, (_Float16)v.w};
  *(f16x4*)(out + (size_t)j * 4) = o;
}

// ---------------- all 4 weights: W [K][N] f32 -> Wt [N][K] f16, one launch ----------------
__global__ __launch_bounds__(256) void wtrans4(const float* __restrict__ Wq,
                                               const float* __restrict__ Wk,
                                               const float* __restrict__ Wv,
                                               const float* __restrict__ Wo,
                                               _Float16* __restrict__ WqT,
                                               _Float16* __restrict__ WkT,
                                               _Float16* __restrict__ WvT,
                                               _Float16* __restrict__ WoT) {
  __shared__ float tile[32][33];
  int which = blockIdx.x >> 10;
  const float* W = (which == 0) ? Wq : (which == 1) ? Wk : (which == 2) ? Wv : Wo;
  _Float16* Wt   = (which == 0) ? WqT : (which == 1) ? WkT : (which == 2) ? WvT : WoT;
  int idx = blockIdx.x & 1023;
  int bx = idx & 31, by = idx >> 5;
  int tx = threadIdx.x & 31, ty = threadIdx.x >> 5;  // ty 0..7
#pragma unroll
  for (int j = 0; j < 4; ++j)
    tile[ty + j * 8][tx] = W[(size_t)(by * 32 + ty + j * 8) * 1024 + bx * 32 + tx];
  __syncthreads();
#pragma unroll
  for (int j = 0; j < 4; ++j)
    Wt[(size_t)(bx * 32 + ty + j * 8) * 1024 + by * 32 + tx] = (_Float16)tile[tx][ty + j * 8];
}

// ---------------- GEMM: C[M][N] = A[M][K] @ Bt[N][K]^T (m97 structure) ----------------
template <int F32OUT>
__global__ __launch_bounds__(256, 2) void gemm_bt(const _Float16* __restrict__ A,
                                                  const _Float16* __restrict__ Bt,
                                                  void* __restrict__ Cp,
                                                  int M, int N, int K) {
  __shared__ _Float16 As[128 * 32];
  __shared__ _Float16 Bs[128 * 32];
  const int nbn = N >> 7;
  const int bm = blockIdx.x / nbn, bn = blockIdx.x % nbn;
  const int t = threadIdx.x, w = t >> 6, l = t & 63;
  const int lr = l & 15, lg = l >> 4;
  const int wr = w >> 1, wc = w & 1;
  const int m0 = bm << 7, n0 = bn << 7;

  f32x4 acc[4][4] = {};

  for (int k0 = 0; k0 < K; k0 += 32) {
#pragma unroll
    for (int p = 0; p < 2; ++p) {
      int off = p * 4096 + w * 1024 + l * 16;  // linear byte offset in 8KB tile
      int row = off >> 6;                       // 64B per row (32 f16)
      int col = (off & 63) >> 1;                // element col
      gload_lds16(A  + (size_t)(m0 + row) * K + k0 + col, (char*)As + p * 4096 + w * 1024);
      gload_lds16(Bt + (size_t)(n0 + row) * K + k0 + col, (char*)Bs + p * 4096 + w * 1024);
    }
    __syncthreads();
    f16x8 af[4], bq[4];
#pragma unroll
    for (int i = 0; i < 4; ++i) {
      af[i] = *(const f16x8*)((const char*)As + (wr * 64 + i * 16 + lr) * 64 + lg * 16);
      bq[i] = *(const f16x8*)((const char*)Bs + (wc * 64 + i * 16 + lr) * 64 + lg * 16);
    }
#pragma unroll
    for (int i = 0; i < 4; ++i)
#pragma unroll
      for (int j = 0; j < 4; ++j)
        acc[i][j] = __builtin_amdgcn_mfma_f32_16x16x32_f16(af[i], bq[j], acc[i][j], 0, 0, 0);
    __syncthreads();
  }
#pragma unroll
  for (int i = 0; i < 4; ++i)
#pragma unroll
    for (int j = 0; j < 4; ++j)
#pragma unroll
      for (int r = 0; r < 4; ++r) {
        size_t row = m0 + wr * 64 + i * 16 + lg * 4 + r;
        size_t col = n0 + wc * 64 + j * 16 + lr;
        if (F32OUT) ((float*)Cp)[row * N + col] = acc[i][j][r];
        else ((_Float16*)Cp)[row * N + col] = (_Float16)acc[i][j][r];
      }
}

// ---------------- V [b][kv][1024+h*64+d] -> Vt [b][h][d][kv] ----------------
__global__ __launch_bounds__(256) void vtrans(const _Float16* __restrict__ KVb,
                                              _Float16* __restrict__ Vt) {
  __shared__ _Float16 tile[64][72];  // [kv][d], padded rows (144B, 16B-aligned)
  int idx = blockIdx.x;
  int kt = idx & 31, h = (idx >> 5) & 15, b = idx >> 9;
  int kv0 = kt << 6;
  int t = threadIdx.x;
#pragma unroll
  for (int p = 0; p < 2; ++p) {
    int c = t + p * 256;
    int row = c >> 3, cb = (c & 7) * 16;
    f16x8 v = *(const f16x8*)(KVb + (size_t)(b * NKV_ + kv0 + row) * DKV_ + 1024 + h * 64 + cb / 2);
    *(f16x8*)((char*)&tile[row][0] + cb) = v;
  }
  __syncthreads();
  int d = t & 63, j0 = (t >> 6) * 2;
#pragma unroll
  for (int jj = 0; jj < 2; ++jj) {
    int kvs = (j0 + jj) * 8;
    f16x8 o;
#pragma unroll
    for (int u = 0; u < 8; ++u) o[u] = tile[kvs + u][d];
    *(f16x8*)(Vt + ((size_t)((b * H_ + h) * 64 + d)) * NKV_ + kv0 + kvs) = o;
  }
}

// ---------------- fused attention: softmax(Q K^T + bias) V ----------------
// Round-7 structure (single-buffer 24KB LDS, 2 barriers/iter, swapped-operand
// 16x16 MFMA, lane-local q softmax, defer-max, exp2 domain, no grid swizzle)
// + BIAS PREFETCHED ONE FULL TILE AHEAD (bvA/bvB rotation via 2x unroll):
// bias comes from L3 (~500cyc); issuing it an iteration early gives softmax+PV
// +staging (~500cyc) of cover instead of just the QK^T cluster (~120cyc).
__global__ __launch_bounds__(256, 4) void attn(const _Float16* __restrict__ Qb,
                                               const _Float16* __restrict__ KVb,
                                               const _Float16* __restrict__ Vt,
                                               const float* __restrict__ bias,
                                               _Float16* __restrict__ ctx) {
  __shared__ _Float16 Ks[64 * 64];      // [kv][d], XOR-swizzled rows
  __shared__ _Float16 Vs[64 * 64];      // [d][kv], XOR-swizzled rows
  __shared__ _Float16 Ps[4][16 * 64];   // per-wave P^T as [q][kv], XOR-swizzled
  const float LOG2E = 1.44269504f;
  int idx = blockIdx.x;
  int b = idx & 3, qt = (idx >> 2) & 31, hd = idx >> 7;  // batch innermost (L3-proven order)
  int t = threadIdx.x, w = t >> 6, l = t & 63, lr = l & 15, lg = l >> 4;
  int qw = (qt << 6) + (w << 4);

  const _Float16* qp = Qb + (size_t)(b * NQ_ + qw + lr) * DM_ + hd * 64 + lg * 8;
  f16x8 aq0 = *(const f16x8*)qp;
  f16x8 aq1 = *(const f16x8*)(qp + 32);
  // pre-scale Q by log2(e): QK^T lands directly in exp2 domain
#pragma unroll
  for (int u = 0; u < 8; ++u) { aq0[u] = aq0[u] * (_Float16)LOG2E; aq1[u] = aq1[u] * (_Float16)LOG2E; }

  f32x4 acc[4] = {};          // acc^T: [d-tile nt][r], d = nt*16+lg*4+r, q = lr
  float mrow = -1e30f;        // running max for q = qw+lr (exp2 domain)
  float lsum = 0.f;

  const _Float16* Kbase = KVb + (size_t)b * NKV_ * DKV_ + hd * 64;
  const _Float16* Vtb   = Vt + (size_t)(b * H_ + hd) * 64 * NKV_;
  const float*    biasq = bias + ((size_t)hd * NQ_ + qw + lr) * NKV_ + lg * 4;  // per-lane q row

  const int srow = t >> 3;        // staging row (p adds 32)
  const int scb  = (t & 7) * 16;  // staging byte col within 128B row

  f16x8 kreg[2], vreg[2];
  float4 bvA[4], bvB[4];

  auto LOADKV = [&](int kv0) {
#pragma unroll
    for (int p = 0; p < 2; ++p) {
      int row = srow + p * 32;
      kreg[p] = *(const f16x8*)(Kbase + (size_t)(kv0 + row) * DKV_ + scb / 2);
      vreg[p] = *(const f16x8*)(Vtb + (size_t)row * NKV_ + kv0 + scb / 2);
    }
  };
  auto LOADBIAS = [&](int kv0, float4 (&dst)[4]) {
#pragma unroll
    for (int nt = 0; nt < 4; ++nt)
      dst[nt] = *(const float4*)(biasq + kv0 + nt * 16);
  };

  auto BODY = [&](float4 (&bv)[4], float4 (&bvn)[4], int it) {
    const int kv0 = it << 6;

    // ---- write staged regs (tile it) to LDS ----
#pragma unroll
    for (int p = 0; p < 2; ++p) {
      int row = srow + p * 32;
      int off = (row * 128 + scb) ^ ((row & 7) << 4);
      *(f16x8*)((char*)Ks + off) = kreg[p];
      *(f16x8*)((char*)Vs + off) = vreg[p];
    }
    __syncthreads();

    // ---- issue next tile's global K/V loads (consumed next iteration) ----
    const int kvn = (it < 31) ? kv0 + 64 : kv0;
    LOADKV(kvn);

    // ---- S^T = K Q^T: lane holds S[kv = nt*16+lg*4+r][q = lr] ----
    f32x4 s[4];
    __builtin_amdgcn_s_setprio(1);
#pragma unroll
    for (int nt = 0; nt < 4; ++nt) {
      int row = nt * 16 + lr;
      int sw = (row & 7) << 4;
      f16x8 kf0 = *(const f16x8*)((char*)Ks + ((row * 128 + lg * 16) ^ sw));
      f16x8 kf1 = *(const f16x8*)((char*)Ks + ((row * 128 + 64 + lg * 16) ^ sw));
      f32x4 z = {0.f, 0.f, 0.f, 0.f};
      z = __builtin_amdgcn_mfma_f32_16x16x32_f16(kf0, aq0, z, 0, 0, 0);
      s[nt] = __builtin_amdgcn_mfma_f32_16x16x32_f16(kf1, aq1, z, 0, 0, 0);
    }
    __builtin_amdgcn_s_setprio(0);

    // ---- + bias (prefetched LAST iteration; exp2 domain via fma) ----
#pragma unroll
    for (int nt = 0; nt < 4; ++nt) {
      s[nt][0] = fmaf(bv[nt].x, LOG2E, s[nt][0]);
      s[nt][1] = fmaf(bv[nt].y, LOG2E, s[nt][1]);
      s[nt][2] = fmaf(bv[nt].z, LOG2E, s[nt][2]);
      s[nt][3] = fmaf(bv[nt].w, LOG2E, s[nt][3]);
    }
    // ---- prefetch NEXT tile's bias (L3 latency covered by softmax+PV+staging) ----
    LOADBIAS(kvn, bvn);

    // ---- row max: max3-triple tree + 2 shuffles (q-row is lane-local) ----
    float m1 = fmaxf(fmaxf(s[0][0], s[0][1]), s[0][2]);
    float m2 = fmaxf(fmaxf(s[0][3], s[1][0]), s[1][1]);
    float m3 = fmaxf(fmaxf(s[1][2], s[1][3]), s[2][0]);
    float m4 = fmaxf(fmaxf(s[2][1], s[2][2]), s[2][3]);
    float m5 = fmaxf(fmaxf(s[3][0], s[3][1]), s[3][2]);
    float m6 = fmaxf(fmaxf(m1, m2), s[3][3]);
    float m7 = fmaxf(fmaxf(m3, m4), m5);
    float pmax = fmaxf(m6, m7);
    pmax = fmaxf(pmax, __shfl_xor(pmax, 16));
    pmax = fmaxf(pmax, __shfl_xor(pmax, 32));

    // ---- defer-max: rescale only when max grew past THR=8 (P <= 2^8, f16-safe) ----
    if (__any(pmax > mrow + 8.0f)) {
      float mn = fmaxf(mrow, pmax);
      float corr = exp2f(mrow - mn);
      mrow = mn;
      lsum *= corr;
#pragma unroll
      for (int nt = 0; nt < 4; ++nt)
#pragma unroll
        for (int r = 0; r < 4; ++r) acc[nt][r] *= corr;
    }

    // ---- P = exp2(S - mrow); row sum: 15 in-lane + 2 shuffles ----
    float rs = 0.f;
#pragma unroll
    for (int nt = 0; nt < 4; ++nt)
#pragma unroll
      for (int r = 0; r < 4; ++r) {
        float p = exp2f(s[nt][r] - mrow);
        s[nt][r] = p;
        rs += p;
      }
    rs += __shfl_xor(rs, 16);
    rs += __shfl_xor(rs, 32);
    lsum += rs;

    // ---- P^T -> per-wave LDS [q][kv] as 4x f16x4 (8B) writes ----
#pragma unroll
    for (int nt = 0; nt < 4; ++nt) {
      f16x4 pk = {(_Float16)s[nt][0], (_Float16)s[nt][1],
                  (_Float16)s[nt][2], (_Float16)s[nt][3]};
      int off = (lr * 128 + nt * 32 + lg * 8) ^ ((lr & 7) << 4);
      *(f16x4*)((char*)Ps[w] + off) = pk;
    }

    // ---- PV swapped: acc^T = mfma(V^T-frag, P^T-frag) ----
    __builtin_amdgcn_s_setprio(1);
#pragma unroll
    for (int kk = 0; kk < 2; ++kk) {
      f16x8 pb = *(const f16x8*)((char*)Ps[w] +
                 ((lr * 128 + kk * 64 + lg * 16) ^ ((lr & 7) << 4)));
#pragma unroll
      for (int nt = 0; nt < 4; ++nt) {
        int row = nt * 16 + lr;
        f16x8 vf = *(const f16x8*)((char*)Vs +
                 ((row * 128 + kk * 64 + lg * 16) ^ ((row & 7) << 4)));
        acc[nt] = __builtin_amdgcn_mfma_f32_16x16x32_f16(vf, pb, acc[nt], 0, 0, 0);
      }
    }
    __builtin_amdgcn_s_setprio(0);
    __syncthreads();
  };

  // prologue: tile0 K/V -> regs; tile0 bias -> bvA
  LOADKV(0);
  LOADBIAS(0, bvA);

  for (int i2 = 0; i2 < 16; ++i2) {
    BODY(bvA, bvB, i2 * 2);
    BODY(bvB, bvA, i2 * 2 + 1);
  }

  // ---- normalize + write ctx[b][q=qw+lr][hd*64 + nt*16+lg*4+{0..3}] (8B stores) ----
  float inv = 1.0f / lsum;
#pragma unroll
  for (int nt = 0; nt < 4; ++nt) {
    f16x4 o = {(_Float16)(acc[nt][0] * inv), (_Float16)(acc[nt][1] * inv),
               (_Float16)(acc[nt][2] * inv), (_Float16)(acc[nt][3] * inv)};
    *(f16x4*)(ctx + ((size_t)b * NQ_ + qw + lr) * DM_ + hd * 64 + nt * 16 + lg * 4) = o;
  }
}

extern "C" void kernel_launch(void* const* d_in, const int* in_sizes, int n_in,
                              void* d_out, int out_size, void* d_ws, size_t ws_size,
                              hipStream_t stream) {
  const float* x    = (const float*)d_in[0];
  const float* enc  = (const float*)d_in[1];
  const float* bias = (const float*)d_in[2];
  const float* Wq   = (const float*)d_in[3];
  const float* Wk   = (const float*)d_in[4];
  const float* Wv   = (const float*)d_in[5];
  const float* Wo   = (const float*)d_in[6];
  char* ws = (char*)d_ws;
  const size_t MiB = 1024 * 1024;
  _Float16* WqT   = (_Float16*)(ws + 0 * MiB);
  _Float16* WkT   = (_Float16*)(ws + 2 * MiB);   // WkT+WvT contiguous: stacked Bt [2048][1024]
  _Float16* WvT   = (_Float16*)(ws + 4 * MiB);
  _Float16* WoT   = (_Float16*)(ws + 6 * MiB);
  _Float16* xf    = (_Float16*)(ws + 8 * MiB);
  _Float16* encf  = (_Float16*)(ws + 24 * MiB);
  _Float16* Qb    = (_Float16*)(ws + 40 * MiB);
  _Float16* KVb   = (_Float16*)(ws + 56 * MiB);  // [8192][2048]: cols 0..1023=K, 1024..2047=V
  _Float16* Vt    = (_Float16*)(ws + 88 * MiB);  // [B][H][64][NKV]
  _Float16* ctxf  = (_Float16*)(ws + 104 * MiB); // [8192][1024]

  wtrans4<<<4096, 256, 0, stream>>>(Wq, Wk, Wv, Wo, WqT, WkT, WvT, WoT);
  cast2_f16<<<16384, 256, 0, stream>>>(x, enc, xf, encf);
  gemm_bt<0><<<512, 256, 0, stream>>>(xf, WqT, Qb, 8192, 1024, 1024);
  gemm_bt<0><<<1024, 256, 0, stream>>>(encf, WkT, KVb, 8192, 2048, 1024);
  vtrans<<<2048, 256, 0, stream>>>(KVb, Vt);
  attn<<<2048, 256, 0, stream>>>(Qb, KVb, Vt, bias, ctxf);
  gemm_bt<1><<<512, 256, 0, stream>>>(ctxf, WoT, d_out, 8192, 1024, 1024);
}

// Round 14
// 345.102 us; speedup vs baseline: 1.5743x; 1.0017x over previous
//
#include <hip/hip_runtime.h>

// Problem constants
#define B_   4
#define NQ_  2048
#define NKV_ 2048
#define H_   16
#define DK_  64
#define DM_  1024
#define DKV_ 2048   // stacked K|V projection width

typedef _Float16 f16x8 __attribute__((ext_vector_type(8)));
typedef _Float16 f16x4 __attribute__((ext_vector_type(4)));
typedef float    f32x4 __attribute__((ext_vector_type(4)));
typedef unsigned u32x4 __attribute__((ext_vector_type(4)));

__device__ __forceinline__ void gload_lds16(const void* g, void* l) {
  __builtin_amdgcn_global_load_lds(
      (const __attribute__((address_space(1))) unsigned int*)g,
      (__attribute__((address_space(3))) unsigned int*)l, 16, 0, 0);
}

// ---------------- cast f32 -> f16 for x and enc in one launch ----------------
__global__ __launch_bounds__(256) void cast2_f16(const float* __restrict__ a,
                                                 const float* __restrict__ b,
                                                 _Float16* __restrict__ ao,
                                                 _Float16* __restrict__ bo) {
  int i = blockIdx.x * 256 + threadIdx.x;       // 4M float4 total (2M each)
  const float* in = (i < 2097152) ? a : b;
  _Float16* out = (i < 2097152) ? ao : bo;
  int j = i & 2097151;
  float4 v = ((const float4*)in)[j];
  f16x4 o = {(_Float16)v.x, (_Float16)v.y, (_Float16)v.z, (_Float16)v.w};
  *(f16x4*)(out + (size_t)j * 4) = o;
}

// ---------------- all 4 weights: W [K][N] f32 -> Wt [N][K] f16, one launch ----------------
__global__ __launch_bounds__(256) void wtrans4(const float* __restrict__ Wq,
                                               const float* __restrict__ Wk,
                                               const float* __restrict__ Wv,
                                               const float* __restrict__ Wo,
                                               _Float16* __restrict__ WqT,
                                               _Float16* __restrict__ WkT,
                                               _Float16* __restrict__ WvT,
                                               _Float16* __restrict__ WoT) {
  __shared__ float tile[32][33];
  int which = blockIdx.x >> 10;
  const float* W = (which == 0) ? Wq : (which == 1) ? Wk : (which == 2) ? Wv : Wo;
  _Float16* Wt   = (which == 0) ? WqT : (which == 1) ? WkT : (which == 2) ? WvT : WoT;
  int idx = blockIdx.x & 1023;
  int bx = idx & 31, by = idx >> 5;
  int tx = threadIdx.x & 31, ty = threadIdx.x >> 5;  // ty 0..7
#pragma unroll
  for (int j = 0; j < 4; ++j)
    tile[ty + j * 8][tx] = W[(size_t)(by * 32 + ty + j * 8) * 1024 + bx * 32 + tx];
  __syncthreads();
#pragma unroll
  for (int j = 0; j < 4; ++j)
    Wt[(size_t)(bx * 32 + ty + j * 8) * 1024 + by * 32 + tx] = (_Float16)tile[tx][ty + j * 8];
}

// ---------------- GEMM: C[M][N] = A[M][K] @ Bt[N][K]^T (m97 structure) ----------------
template <int F32OUT>
__global__ __launch_bounds__(256, 2) void gemm_bt(const _Float16* __restrict__ A,
                                                  const _Float16* __restrict__ Bt,
                                                  void* __restrict__ Cp,
                                                  int M, int N, int K) {
  __shared__ _Float16 As[128 * 32];
  __shared__ _Float16 Bs[128 * 32];
  const int nbn = N >> 7;
  const int bm = blockIdx.x / nbn, bn = blockIdx.x % nbn;
  const int t = threadIdx.x, w = t >> 6, l = t & 63;
  const int lr = l & 15, lg = l >> 4;
  const int wr = w >> 1, wc = w & 1;
  const int m0 = bm << 7, n0 = bn << 7;

  f32x4 acc[4][4] = {};

  for (int k0 = 0; k0 < K; k0 += 32) {
#pragma unroll
    for (int p = 0; p < 2; ++p) {
      int off = p * 4096 + w * 1024 + l * 16;  // linear byte offset in 8KB tile
      int row = off >> 6;                       // 64B per row (32 f16)
      int col = (off & 63) >> 1;                // element col
      gload_lds16(A  + (size_t)(m0 + row) * K + k0 + col, (char*)As + p * 4096 + w * 1024);
      gload_lds16(Bt + (size_t)(n0 + row) * K + k0 + col, (char*)Bs + p * 4096 + w * 1024);
    }
    __syncthreads();
    f16x8 af[4], bq[4];
#pragma unroll
    for (int i = 0; i < 4; ++i) {
      af[i] = *(const f16x8*)((const char*)As + (wr * 64 + i * 16 + lr) * 64 + lg * 16);
      bq[i] = *(const f16x8*)((const char*)Bs + (wc * 64 + i * 16 + lr) * 64 + lg * 16);
    }
#pragma unroll
    for (int i = 0; i < 4; ++i)
#pragma unroll
      for (int j = 0; j < 4; ++j)
        acc[i][j] = __builtin_amdgcn_mfma_f32_16x16x32_f16(af[i], bq[j], acc[i][j], 0, 0, 0);
    __syncthreads();
  }
#pragma unroll
  for (int i = 0; i < 4; ++i)
#pragma unroll
    for (int j = 0; j < 4; ++j)
#pragma unroll
      for (int r = 0; r < 4; ++r) {
        size_t row = m0 + wr * 64 + i * 16 + lg * 4 + r;
        size_t col = n0 + wc * 64 + j * 16 + lr;
        if (F32OUT) ((float*)Cp)[row * N + col] = acc[i][j][r];
        else ((_Float16*)Cp)[row * N + col] = (_Float16)acc[i][j][r];
      }
}

// ---- V [b][kv][1024+h*64+d] -> Vt [b][h][d][p], p = permuted kv within each 64-block:
//      kv(p) = 32*(p>>5) + 16*((p>>2)&1) + 4*((p>>3)&3) + (p&3)
//      (chosen so attn's PV B-fragment is lane-local QK^T output — no P LDS round-trip)
__global__ __launch_bounds__(256) void vtrans(const _Float16* __restrict__ KVb,
                                              _Float16* __restrict__ Vt) {
  __shared__ _Float16 tile[64][72];  // [kv][d], padded rows (144B, 16B-aligned)
  int idx = blockIdx.x;
  int kt = idx & 31, h = (idx >> 5) & 15, b = idx >> 9;
  int kv0 = kt << 6;
  int t = threadIdx.x;
#pragma unroll
  for (int p = 0; p < 2; ++p) {
    int c = t + p * 256;
    int row = c >> 3, cb = (c & 7) * 16;
    f16x8 v = *(const f16x8*)(KVb + (size_t)(b * NKV_ + kv0 + row) * DKV_ + 1024 + h * 64 + cb / 2);
    *(f16x8*)((char*)&tile[row][0] + cb) = v;
  }
  __syncthreads();
  int d = t & 63, j0 = (t >> 6) * 2;
#pragma unroll
  for (int jj = 0; jj < 2; ++jj) {
    int p0 = (j0 + jj) * 8;
    f16x8 o;
#pragma unroll
    for (int u = 0; u < 8; ++u) {
      int p = p0 + u;
      int kv = ((p >> 5) << 5) + (((p >> 2) & 1) << 4) + (((p >> 3) & 3) << 2) + (p & 3);
      o[u] = tile[kv][d];
    }
    *(f16x8*)(Vt + ((size_t)((b * H_ + h) * 64 + d)) * NKV_ + kv0 + p0) = o;
  }
}

// ---------------- fused attention: softmax(Q K^T + bias) V ----------------
// Round-13 structure (single-buffer LDS, 2 barriers/iter, swapped-operand
// 16x16 MFMA, lane-local q softmax, defer-max, exp2, bias prefetch) with the
// P LDS ROUND-TRIP ELIMINATED: V columns are pre-permuted (vtrans) so the PV
// B-fragment = lane-local cvt_pkrtz packs of the QK^T output. LDS 16KB.
__global__ __launch_bounds__(256, 4) void attn(const _Float16* __restrict__ Qb,
                                               const _Float16* __restrict__ KVb,
                                               const _Float16* __restrict__ Vt,
                                               const float* __restrict__ bias,
                                               _Float16* __restrict__ ctx) {
  __shared__ _Float16 Ks[64 * 64];      // [kv][d], XOR-swizzled rows
  __shared__ _Float16 Vs[64 * 64];      // [d][p],  XOR-swizzled rows (p = permuted kv)
  const float LOG2E = 1.44269504f;
  int idx = blockIdx.x;
  int b = idx & 3, qt = (idx >> 2) & 31, hd = idx >> 7;  // batch innermost (L3-proven order)
  int t = threadIdx.x, w = t >> 6, l = t & 63, lr = l & 15, lg = l >> 4;
  int qw = (qt << 6) + (w << 4);

  const _Float16* qp = Qb + (size_t)(b * NQ_ + qw + lr) * DM_ + hd * 64 + lg * 8;
  f16x8 aq0 = *(const f16x8*)qp;
  f16x8 aq1 = *(const f16x8*)(qp + 32);
  // pre-scale Q by log2(e): QK^T lands directly in exp2 domain
#pragma unroll
  for (int u = 0; u < 8; ++u) { aq0[u] = aq0[u] * (_Float16)LOG2E; aq1[u] = aq1[u] * (_Float16)LOG2E; }

  f32x4 acc[4] = {};          // acc^T: [d-tile nt][r], d = nt*16+lg*4+r, q = lr
  float mrow = -1e30f;        // running max for q = qw+lr (exp2 domain)
  float lsum = 0.f;

  const _Float16* Kbase = KVb + (size_t)b * NKV_ * DKV_ + hd * 64;
  const _Float16* Vtb   = Vt + (size_t)(b * H_ + hd) * 64 * NKV_;
  const float*    biasq = bias + ((size_t)hd * NQ_ + qw + lr) * NKV_ + lg * 4;  // per-lane q row

  const int srow = t >> 3;        // staging row (p adds 32)
  const int scb  = (t & 7) * 16;  // staging byte col within 128B row

  f16x8 kreg[2], vreg[2];
  float4 bvA[4], bvB[4];

  auto LOADKV = [&](int kv0) {
#pragma unroll
    for (int p = 0; p < 2; ++p) {
      int row = srow + p * 32;
      kreg[p] = *(const f16x8*)(Kbase + (size_t)(kv0 + row) * DKV_ + scb / 2);
      vreg[p] = *(const f16x8*)(Vtb + (size_t)row * NKV_ + kv0 + scb / 2);
    }
  };
  auto LOADBIAS = [&](int kv0, float4 (&dst)[4]) {
#pragma unroll
    for (int nt = 0; nt < 4; ++nt)
      dst[nt] = *(const float4*)(biasq + kv0 + nt * 16);
  };

  auto BODY = [&](float4 (&bv)[4], float4 (&bvn)[4], int it) {
    const int kv0 = it << 6;

    // ---- write staged regs (tile it) to LDS ----
#pragma unroll
    for (int p = 0; p < 2; ++p) {
      int row = srow + p * 32;
      int off = (row * 128 + scb) ^ ((row & 7) << 4);
      *(f16x8*)((char*)Ks + off) = kreg[p];
      *(f16x8*)((char*)Vs + off) = vreg[p];
    }
    __syncthreads();

    // ---- issue next tile's global K/V loads (consumed next iteration) ----
    const int kvn = (it < 31) ? kv0 + 64 : kv0;
    LOADKV(kvn);

    // ---- S^T = K Q^T: lane holds S[kv = nt*16+lg*4+r][q = lr] ----
    f32x4 s[4];
    __builtin_amdgcn_s_setprio(1);
#pragma unroll
    for (int nt = 0; nt < 4; ++nt) {
      int row = nt * 16 + lr;
      int sw = (row & 7) << 4;
      f16x8 kf0 = *(const f16x8*)((char*)Ks + ((row * 128 + lg * 16) ^ sw));
      f16x8 kf1 = *(const f16x8*)((char*)Ks + ((row * 128 + 64 + lg * 16) ^ sw));
      f32x4 z = {0.f, 0.f, 0.f, 0.f};
      z = __builtin_amdgcn_mfma_f32_16x16x32_f16(kf0, aq0, z, 0, 0, 0);
      s[nt] = __builtin_amdgcn_mfma_f32_16x16x32_f16(kf1, aq1, z, 0, 0, 0);
    }
    __builtin_amdgcn_s_setprio(0);

    // ---- + bias (prefetched LAST iteration; exp2 domain via fma) ----
#pragma unroll
    for (int nt = 0; nt < 4; ++nt) {
      s[nt][0] = fmaf(bv[nt].x, LOG2E, s[nt][0]);
      s[nt][1] = fmaf(bv[nt].y, LOG2E, s[nt][1]);
      s[nt][2] = fmaf(bv[nt].z, LOG2E, s[nt][2]);
      s[nt][3] = fmaf(bv[nt].w, LOG2E, s[nt][3]);
    }
    // ---- prefetch NEXT tile's bias (L3 latency covered by softmax+PV+staging) ----
    LOADBIAS(kvn, bvn);

    // ---- row max: max3-triple tree + 2 shuffles (q-row is lane-local) ----
    float m1 = fmaxf(fmaxf(s[0][0], s[0][1]), s[0][2]);
    float m2 = fmaxf(fmaxf(s[0][3], s[1][0]), s[1][1]);
    float m3 = fmaxf(fmaxf(s[1][2], s[1][3]), s[2][0]);
    float m4 = fmaxf(fmaxf(s[2][1], s[2][2]), s[2][3]);
    float m5 = fmaxf(fmaxf(s[3][0], s[3][1]), s[3][2]);
    float m6 = fmaxf(fmaxf(m1, m2), s[3][3]);
    float m7 = fmaxf(fmaxf(m3, m4), m5);
    float pmax = fmaxf(m6, m7);
    pmax = fmaxf(pmax, __shfl_xor(pmax, 16));
    pmax = fmaxf(pmax, __shfl_xor(pmax, 32));

    // ---- defer-max: rescale only when max grew past THR=8 (P <= 2^8, f16-safe) ----
    if (__any(pmax > mrow + 8.0f)) {
      float mn = fmaxf(mrow, pmax);
      float corr = exp2f(mrow - mn);
      mrow = mn;
      lsum *= corr;
#pragma unroll
      for (int nt = 0; nt < 4; ++nt)
#pragma unroll
        for (int r = 0; r < 4; ++r) acc[nt][r] *= corr;
    }

    // ---- P = exp2(S - mrow); row sum: 15 in-lane + 2 shuffles ----
    float rs = 0.f;
#pragma unroll
    for (int nt = 0; nt < 4; ++nt)
#pragma unroll
      for (int r = 0; r < 4; ++r) {
        float p = exp2f(s[nt][r] - mrow);
        s[nt][r] = p;
        rs += p;
      }
    rs += __shfl_xor(rs, 16);
    rs += __shfl_xor(rs, 32);
    lsum += rs;

    // ---- pack P lane-locally: dwp[nt][j] = pkrtz(s[nt][2j], s[nt][2j+1]) ----
    unsigned dwp[4][2];
#pragma unroll
    for (int nt = 0; nt < 4; ++nt)
#pragma unroll
      for (int j = 0; j < 2; ++j)
        dwp[nt][j] = __builtin_bit_cast(unsigned,
            __builtin_amdgcn_cvt_pkrtz(s[nt][2 * j], s[nt][2 * j + 1]));

    // ---- PV: pb IS the QK^T output (V columns pre-permuted to match) ----
    __builtin_amdgcn_s_setprio(1);
#pragma unroll
    for (int kk = 0; kk < 2; ++kk) {
      u32x4 pv = {dwp[2 * kk][0], dwp[2 * kk][1], dwp[2 * kk + 1][0], dwp[2 * kk + 1][1]};
      f16x8 pb = __builtin_bit_cast(f16x8, pv);
#pragma unroll
      for (int nt = 0; nt < 4; ++nt) {
        int row = nt * 16 + lr;
        f16x8 vf = *(const f16x8*)((char*)Vs +
                 ((row * 128 + kk * 64 + lg * 16) ^ ((row & 7) << 4)));
        acc[nt] = __builtin_amdgcn_mfma_f32_16x16x32_f16(vf, pb, acc[nt], 0, 0, 0);
      }
    }
    __builtin_amdgcn_s_setprio(0);
    __syncthreads();
  };

  // prologue: tile0 K/V -> regs; tile0 bias -> bvA
  LOADKV(0);
  LOADBIAS(0, bvA);

  for (int i2 = 0; i2 < 16; ++i2) {
    BODY(bvA, bvB, i2 * 2);
    BODY(bvB, bvA, i2 * 2 + 1);
  }

  // ---- normalize + write ctx[b][q=qw+lr][hd*64 + nt*16+lg*4+{0..3}] (8B stores) ----
  float inv = 1.0f / lsum;
#pragma unroll
  for (int nt = 0; nt < 4; ++nt) {
    f16x4 o = {(_Float16)(acc[nt][0] * inv), (_Float16)(acc[nt][1] * inv),
               (_Float16)(acc[nt][2] * inv), (_Float16)(acc[nt][3] * inv)};
    *(f16x4*)(ctx + ((size_t)b * NQ_ + qw + lr) * DM_ + hd * 64 + nt * 16 + lg * 4) = o;
  }
}

extern "C" void kernel_launch(void* const* d_in, const int* in_sizes, int n_in,
                              void* d_out, int out_size, void* d_ws, size_t ws_size,
                              hipStream_t stream) {
  const float* x    = (const float*)d_in[0];
  const float* enc  = (const float*)d_in[1];
  const float* bias = (const float*)d_in[2];
  const float* Wq   = (const float*)d_in[3];
  const float* Wk   = (const float*)d_in[4];
  const float* Wv   = (const float*)d_in[5];
  const float* Wo   = (const float*)d_in[6];
  char* ws = (char*)d_ws;
  const size_t MiB = 1024 * 1024;
  _Float16* WqT   = (_Float16*)(ws + 0 * MiB);
  _Float16* WkT   = (_Float16*)(ws + 2 * MiB);   // WkT+WvT contiguous: stacked Bt [2048][1024]
  _Float16* WvT   = (_Float16*)(ws + 4 * MiB);
  _Float16* WoT   = (_Float16*)(ws + 6 * MiB);
  _Float16* xf    = (_Float16*)(ws + 8 * MiB);
  _Float16* encf  = (_Float16*)(ws + 24 * MiB);
  _Float16* Qb    = (_Float16*)(ws + 40 * MiB);
  _Float16* KVb   = (_Float16*)(ws + 56 * MiB);  // [8192][2048]: cols 0..1023=K, 1024..2047=V
  _Float16* Vt    = (_Float16*)(ws + 88 * MiB);  // [B][H][64][NKV], kv-permuted per 64-block
  _Float16* ctxf  = (_Float16*)(ws + 104 * MiB); // [8192][1024]

  wtrans4<<<4096, 256, 0, stream>>>(Wq, Wk, Wv, Wo, WqT, WkT, WvT, WoT);
  cast2_f16<<<16384, 256, 0, stream>>>(x, enc, xf, encf);
  gemm_bt<0><<<512, 256, 0, stream>>>(xf, WqT, Qb, 8192, 1024, 1024);
  gemm_bt<0><<<1024, 256, 0, stream>>>(encf, WkT, KVb, 8192, 2048, 1024);
  vtrans<<<2048, 256, 0, stream>>>(KVb, Vt);
  attn<<<2048, 256, 0, stream>>>(Qb, KVb, Vt, bias, ctxf);
  gemm_bt<1><<<512, 256, 0, stream>>>(ctxf, WoT, d_out, 8192, 1024, 1024);
}